// Round 1
// baseline (498.763 us; speedup 1.0000x reference)
//
#include <hip/hip_runtime.h>
#include <math.h>

#define HID 150
#define EMB 300
#define NOUT 5
#define NNODES 8191
#define NLEAF 4096
#define LEAF_START 4095
#define HSTR 152          // padded H/C row stride (608 B, 16B-aligned rows)
#define XSTR 20           // LDS x-tile stride (80 B rows, 16B-aligned)
#define UCOLS 768         // 750 gate-cols + 18 pad = 256*3 (wave-even col mapping)
#define WCOLS 452         // 450 leaf-cols + 2 pad (1808 B rows)

constexpr int LOSS_BLOCKS = 64;

__device__ __forceinline__ float sigmoidf_(float x) { return 1.0f / (1.0f + __expf(-x)); }

// ---------------- prep: transpose weights to e-major, zero-pad ----------------
// Wt2[e][j], j: 0..149 Wi | 150..299 Wo | 300..449 Wu | 450..451 zero
// Ut2[e][j], j: g*150+h, g: 0=i,1=fl,2=fr,3=o,4=u; e<150 left (U0*), e>=150 right (U1*); 750..767 zero
__global__ __launch_bounds__(256) void prep_kernel(
    const float* __restrict__ Wi, const float* __restrict__ Wo, const float* __restrict__ Wu,
    const float* __restrict__ U0i, const float* __restrict__ U1i,
    const float* __restrict__ U00f, const float* __restrict__ U01f,
    const float* __restrict__ U10f, const float* __restrict__ U11f,
    const float* __restrict__ U0o, const float* __restrict__ U1o,
    const float* __restrict__ U0u, const float* __restrict__ U1u,
    float* __restrict__ Wt2, float* __restrict__ Ut2)
{
    int idx = blockIdx.x * 256 + threadIdx.x;
    if (idx < EMB * WCOLS) {
        int e = idx / WCOLS, j = idx - e * WCOLS;
        float v = 0.f;
        if (j < 450) {
            const float* W; int h;
            if (j < 150)      { W = Wi; h = j; }
            else if (j < 300) { W = Wo; h = j - 150; }
            else              { W = Wu; h = j - 300; }
            v = W[h * EMB + e];
        }
        Wt2[idx] = v;
    }
    if (idx < EMB * UCOLS) {
        int e = idx / UCOLS, j = idx - e * UCOLS;
        float v = 0.f;
        if (j < 750) {
            int g = j / 150, h = j - g * 150;
            if (e < 150) {
                const float* U = (g == 0) ? U0i : (g == 1) ? U00f : (g == 2) ? U10f : (g == 3) ? U0o : U0u;
                v = U[h * HID + e];
            } else {
                const float* U = (g == 0) ? U1i : (g == 1) ? U01f : (g == 2) ? U11f : (g == 3) ? U1o : U1u;
                v = U[h * HID + (e - 150)];
            }
        }
        Ut2[idx] = v;
    }
}

// ---------------- leaf: NB=8 leaves/block, 256 threads, k-split x2 ----------------
// threads: half = tid>>7 owns K-range [half*150, half*150+150); c = tid&127, c<113 owns cols 4c..4c+3.
// Each half accumulates into its own Gs buffer; epilogue sums.
__global__ __launch_bounds__(256) void leaf_v3(
    const float* __restrict__ Wt2,
    const float* __restrict__ bi, const float* __restrict__ bo, const float* __restrict__ bu,
    const float* __restrict__ emb, const int* __restrict__ words,
    float* __restrict__ H, float* __restrict__ C)
{
    constexpr int NB = 8;
    __shared__ __align__(16) float Xs[EMB * XSTR];
    __shared__ __align__(16) float Gs[2][NB][WCOLS];
    const int tid = threadIdx.x;
    const int leaf0 = LEAF_START + blockIdx.x * NB;

    for (int m = 0; m < NB; ++m) {
        const float* src = emb + (long)words[leaf0 + m] * EMB;
        for (int e = tid; e < EMB; e += 256) Xs[e * XSTR + m] = src[e];
    }
    __syncthreads();

    {
        const int half = tid >> 7;
        const int c = tid & 127;
        if (c < 113) {
            float acc[NB][4];
#pragma unroll
            for (int m = 0; m < NB; ++m)
#pragma unroll
                for (int q = 0; q < 4; ++q) acc[m][q] = 0.f;

            const int kbase = half * 150;
            const float* wp = Wt2 + (long)kbase * WCOLS + c * 4;
            const float* xp = Xs + kbase * XSTR;
#pragma unroll 4
            for (int k = 0; k < 150; ++k) {
                float4 w = *(const float4*)(wp + (long)k * WCOLS);
                float x[NB];
#pragma unroll
                for (int m = 0; m < NB; ++m) x[m] = xp[k * XSTR + m];
#pragma unroll
                for (int m = 0; m < NB; ++m) {
                    acc[m][0] = fmaf(x[m], w.x, acc[m][0]);
                    acc[m][1] = fmaf(x[m], w.y, acc[m][1]);
                    acc[m][2] = fmaf(x[m], w.z, acc[m][2]);
                    acc[m][3] = fmaf(x[m], w.w, acc[m][3]);
                }
            }
#pragma unroll
            for (int m = 0; m < NB; ++m)
                *(float4*)&Gs[half][m][c * 4] = make_float4(acc[m][0], acc[m][1], acc[m][2], acc[m][3]);
        }
    }
    __syncthreads();

    for (int p = tid; p < NB * HID; p += 256) {
        int m = p / HID, h = p - m * HID;
        float gi = Gs[0][m][h]       + Gs[1][m][h];
        float go = Gs[0][m][150 + h] + Gs[1][m][150 + h];
        float gu = Gs[0][m][300 + h] + Gs[1][m][300 + h];
        float ig = sigmoidf_(gi + bi[h]);
        float og = sigmoidf_(go + bo[h]);
        float uv = tanhf(gu + bu[h]);
        float cc = ig * uv;
        float hh = og * tanhf(cc);
        long node = leaf0 + m;
        H[node * HSTR + h] = hh;
        C[node * HSTR + h] = cc;
    }
}

// ---------------- internal level: NB nodes/block, 512 threads, k-split x2, 3-col-strided ----------------
// half = tid>>8 owns K-range [half*150,+150); c = tid&255 owns cols {c, c+256, c+512} of UCOLS=768.
// ALL 512 threads active -> 8 equal waves, 2/SIMD, even packing.
template<int NB>
__global__ __launch_bounds__(512) void level_v3(
    const float* __restrict__ Ut2,
    const float* __restrict__ bbi, const float* __restrict__ bbf,
    const float* __restrict__ bbo, const float* __restrict__ bbu,
    const int* __restrict__ lchs, const int* __restrict__ rchs,
    float* __restrict__ H, float* __restrict__ C, int s, int count)
{
    __shared__ __align__(16) float Xs[EMB * XSTR];
    __shared__ __align__(16) float Gs[2][NB][UCOLS];
    __shared__ int lidx[NB], ridx[NB];
    const int tid = threadIdx.x;
    const int node0 = s + blockIdx.x * NB;
    int nb = count - blockIdx.x * NB; if (nb > NB) nb = NB;

    if (tid < NB) {
        int mm = tid < nb ? tid : 0;
        lidx[tid] = lchs[node0 + mm];
        ridx[tid] = rchs[node0 + mm];
    }
    __syncthreads();

    for (int m = 0; m < NB; ++m) {
        const float* hl = H + (long)lidx[m] * HSTR;
        const float* hr = H + (long)ridx[m] * HSTR;
        for (int e = tid; e < EMB; e += 512)
            Xs[e * XSTR + m] = (e < HID) ? hl[e] : hr[e - HID];
    }
    __syncthreads();

    {
        const int half = tid >> 8;
        const int c = tid & 255;
        float acc[NB][3];
#pragma unroll
        for (int m = 0; m < NB; ++m) { acc[m][0] = 0.f; acc[m][1] = 0.f; acc[m][2] = 0.f; }

        const int kbase = half * 150;
        const float* wp = Ut2 + (long)kbase * UCOLS + c;
        const float* xp = Xs + kbase * XSTR;
#pragma unroll 4
        for (int k = 0; k < 150; ++k) {
            float w0 = wp[(long)k * UCOLS];
            float w1 = wp[(long)k * UCOLS + 256];
            float w2 = wp[(long)k * UCOLS + 512];
            float x[NB];
#pragma unroll
            for (int m = 0; m < NB; ++m) x[m] = xp[k * XSTR + m];
#pragma unroll
            for (int m = 0; m < NB; ++m) {
                acc[m][0] = fmaf(x[m], w0, acc[m][0]);
                acc[m][1] = fmaf(x[m], w1, acc[m][1]);
                acc[m][2] = fmaf(x[m], w2, acc[m][2]);
            }
        }
#pragma unroll
        for (int m = 0; m < NB; ++m) {
            Gs[half][m][c]       = acc[m][0];
            Gs[half][m][c + 256] = acc[m][1];
            Gs[half][m][c + 512] = acc[m][2];
        }
    }
    __syncthreads();

    for (int p = tid; p < nb * HID; p += 512) {
        int m = p / HID, h = p - m * HID;
        float gi = Gs[0][m][h]       + Gs[1][m][h];
        float gf0= Gs[0][m][150 + h] + Gs[1][m][150 + h];
        float gf1= Gs[0][m][300 + h] + Gs[1][m][300 + h];
        float go = Gs[0][m][450 + h] + Gs[1][m][450 + h];
        float gu = Gs[0][m][600 + h] + Gs[1][m][600 + h];
        float ig = sigmoidf_(gi + bbi[h]);
        float fl = sigmoidf_(gf0 + bbf[h]);
        float fr = sigmoidf_(gf1 + bbf[h]);
        float og = sigmoidf_(go + bbo[h]);
        float uv = tanhf(gu + bbu[h]);
        float lc = C[(long)lidx[m] * HSTR + h];
        float rc = C[(long)ridx[m] * HSTR + h];
        float cc = ig * uv + fl * lc + fr * rc;
        float hh = og * tanhf(cc);
        long node = node0 + m;
        H[node * HSTR + h] = hh;
        C[node * HSTR + h] = cc;
    }
}

// ---------------- fused tail: levels d=4..0 (31 nodes) in ONE launch, single block ----------------
__global__ __launch_bounds__(512) void tail_v3(
    const float* __restrict__ Ut2,
    const float* __restrict__ bbi, const float* __restrict__ bbf,
    const float* __restrict__ bbo, const float* __restrict__ bbu,
    const int* __restrict__ lchs, const int* __restrict__ rchs,
    float* __restrict__ H, float* __restrict__ C)
{
    constexpr int NB = 8;
    __shared__ __align__(16) float Xs[EMB * XSTR];
    __shared__ __align__(16) float Gs[2][NB][UCOLS];
    __shared__ int lidx[NB], ridx[NB];
    const int tid = threadIdx.x;

    const int ss[5] = {15, 7, 3, 1, 0};
    const int cc[5] = {16, 8, 4, 2, 1};

    for (int li = 0; li < 5; ++li) {
        const int s = ss[li], count = cc[li];
        for (int g0 = 0; g0 < count; g0 += NB) {
            const int node0 = s + g0;
            int nb = count - g0; if (nb > NB) nb = NB;

            __syncthreads();   // protect reuse of shared bufs + order prior global H/C writes
            if (tid < NB) {
                int mm = tid < nb ? tid : 0;
                lidx[tid] = lchs[node0 + mm];
                ridx[tid] = rchs[node0 + mm];
            }
            __syncthreads();

            for (int m = 0; m < NB; ++m) {
                const float* hl = H + (long)lidx[m] * HSTR;
                const float* hr = H + (long)ridx[m] * HSTR;
                for (int e = tid; e < EMB; e += 512)
                    Xs[e * XSTR + m] = (e < HID) ? hl[e] : hr[e - HID];
            }
            __syncthreads();

            {
                const int half = tid >> 8;
                const int c = tid & 255;
                float acc[NB][3];
#pragma unroll
                for (int m = 0; m < NB; ++m) { acc[m][0] = 0.f; acc[m][1] = 0.f; acc[m][2] = 0.f; }

                const int kbase = half * 150;
                const float* wp = Ut2 + (long)kbase * UCOLS + c;
                const float* xp = Xs + kbase * XSTR;
#pragma unroll 4
                for (int k = 0; k < 150; ++k) {
                    float w0 = wp[(long)k * UCOLS];
                    float w1 = wp[(long)k * UCOLS + 256];
                    float w2 = wp[(long)k * UCOLS + 512];
                    float x[NB];
#pragma unroll
                    for (int m = 0; m < NB; ++m) x[m] = xp[k * XSTR + m];
#pragma unroll
                    for (int m = 0; m < NB; ++m) {
                        acc[m][0] = fmaf(x[m], w0, acc[m][0]);
                        acc[m][1] = fmaf(x[m], w1, acc[m][1]);
                        acc[m][2] = fmaf(x[m], w2, acc[m][2]);
                    }
                }
#pragma unroll
                for (int m = 0; m < NB; ++m) {
                    Gs[half][m][c]       = acc[m][0];
                    Gs[half][m][c + 256] = acc[m][1];
                    Gs[half][m][c + 512] = acc[m][2];
                }
            }
            __syncthreads();

            for (int p = tid; p < nb * HID; p += 512) {
                int m = p / HID, h = p - m * HID;
                float gi = Gs[0][m][h]       + Gs[1][m][h];
                float gf0= Gs[0][m][150 + h] + Gs[1][m][150 + h];
                float gf1= Gs[0][m][300 + h] + Gs[1][m][300 + h];
                float go = Gs[0][m][450 + h] + Gs[1][m][450 + h];
                float gu = Gs[0][m][600 + h] + Gs[1][m][600 + h];
                float ig = sigmoidf_(gi + bbi[h]);
                float fl = sigmoidf_(gf0 + bbf[h]);
                float fr = sigmoidf_(gf1 + bbf[h]);
                float og = sigmoidf_(go + bbo[h]);
                float uv = tanhf(gu + bbu[h]);
                float lc = C[(long)lidx[m] * HSTR + h];
                float rc = C[(long)ridx[m] * HSTR + h];
                float cc2 = ig * uv + fl * lc + fr * rc;
                float hh = og * tanhf(cc2);
                long node = node0 + m;
                H[node * HSTR + h] = hh;
                C[node * HSTR + h] = cc2;
            }
        }
    }
}

// ---------------- loss ----------------
__global__ __launch_bounds__(256) void loss_kernel(
    const float* __restrict__ H, const float* __restrict__ Why,
    const float* __restrict__ by, const int* __restrict__ scores,
    float* __restrict__ partials)
{
    __shared__ __align__(16) float Wys[NOUT][HSTR];
    __shared__ float bys[NOUT];
    __shared__ float red[256];
    int tid = threadIdx.x;
    for (int i = tid; i < NOUT * HID; i += 256) {
        int g = i / HID, k = i - g * HID;
        Wys[g][k] = Why[g * HID + k];
    }
    if (tid < NOUT) bys[tid] = by[tid];
    __syncthreads();

    float local = 0.f;
    for (int n = blockIdx.x * 256 + tid; n < NNODES; n += gridDim.x * 256) {
        const float* hr = H + (long)n * HSTR;
        float l0 = bys[0], l1 = bys[1], l2 = bys[2], l3 = bys[3], l4 = bys[4];
        for (int k = 0; k < 148; k += 4) {
            float4 hv = *(const float4*)(hr + k);
            float4 w0 = *(const float4*)&Wys[0][k];
            float4 w1 = *(const float4*)&Wys[1][k];
            float4 w2 = *(const float4*)&Wys[2][k];
            float4 w3 = *(const float4*)&Wys[3][k];
            float4 w4 = *(const float4*)&Wys[4][k];
            l0 += hv.x*w0.x + hv.y*w0.y + hv.z*w0.z + hv.w*w0.w;
            l1 += hv.x*w1.x + hv.y*w1.y + hv.z*w1.z + hv.w*w1.w;
            l2 += hv.x*w2.x + hv.y*w2.y + hv.z*w2.z + hv.w*w2.w;
            l3 += hv.x*w3.x + hv.y*w3.y + hv.z*w3.z + hv.w*w3.w;
            l4 += hv.x*w4.x + hv.y*w4.y + hv.z*w4.z + hv.w*w4.w;
        }
        for (int k = 148; k < HID; ++k) {
            float hv = hr[k];
            l0 += hv * Wys[0][k]; l1 += hv * Wys[1][k]; l2 += hv * Wys[2][k];
            l3 += hv * Wys[3][k]; l4 += hv * Wys[4][k];
        }
        float mx = fmaxf(fmaxf(fmaxf(l0, l1), fmaxf(l2, l3)), l4);
        float se = __expf(l0 - mx) + __expf(l1 - mx) + __expf(l2 - mx) +
                   __expf(l3 - mx) + __expf(l4 - mx);
        float lse = mx + __logf(se);
        int sc = scores[n];
        float lsc = (sc == 0) ? l0 : (sc == 1) ? l1 : (sc == 2) ? l2 : (sc == 3) ? l3 : l4;
        local += lse - lsc;
    }
    red[tid] = local;
    __syncthreads();
    for (int st = 128; st > 0; st >>= 1) {
        if (tid < st) red[tid] += red[tid + st];
        __syncthreads();
    }
    if (tid == 0) partials[blockIdx.x] = red[0];
}

__global__ void loss_final(const float* __restrict__ partials, float* __restrict__ out, int nparts)
{
    if (threadIdx.x == 0 && blockIdx.x == 0) {
        float s = 0.f;
        for (int i = 0; i < nparts; ++i) s += partials[i];
        out[0] = s;
    }
}

extern "C" void kernel_launch(void* const* d_in, const int* in_sizes, int n_in,
                              void* d_out, int out_size, void* d_ws, size_t ws_size,
                              hipStream_t stream)
{
    const float* Wi   = (const float*)d_in[0];
    const float* bi   = (const float*)d_in[1];
    const float* Wo   = (const float*)d_in[2];
    const float* bo   = (const float*)d_in[3];
    const float* Wu   = (const float*)d_in[4];
    const float* bu   = (const float*)d_in[5];
    const float* U0i  = (const float*)d_in[6];
    const float* U1i  = (const float*)d_in[7];
    const float* bbi  = (const float*)d_in[8];
    const float* U00f = (const float*)d_in[9];
    const float* U01f = (const float*)d_in[10];
    const float* U10f = (const float*)d_in[11];
    const float* U11f = (const float*)d_in[12];
    const float* bbf  = (const float*)d_in[13];
    const float* U0o  = (const float*)d_in[14];
    const float* U1o  = (const float*)d_in[15];
    const float* bbo  = (const float*)d_in[16];
    const float* U0u  = (const float*)d_in[17];
    const float* U1u  = (const float*)d_in[18];
    const float* bbu  = (const float*)d_in[19];
    const float* Why  = (const float*)d_in[20];
    const float* by   = (const float*)d_in[21];
    const float* emb  = (const float*)d_in[22];
    const int* scores = (const int*)d_in[23];
    const int* words  = (const int*)d_in[24];
    const int* lchs   = (const int*)d_in[25];
    const int* rchs   = (const int*)d_in[26];

    float* ws = (float*)d_ws;
    float* Wt2 = ws;                                  // 300*452 = 135600
    float* Ut2 = Wt2 + EMB * WCOLS;                   // 300*768 = 230400
    float* H   = Ut2 + EMB * UCOLS;                   // 8191*152
    float* C   = H + (long)NNODES * HSTR;             // 8191*152
    float* partials = C + (long)NNODES * HSTR;        // 64
    float* out = (float*)d_out;

    hipLaunchKernelGGL(prep_kernel, dim3(900), dim3(256), 0, stream,
                       Wi, Wo, Wu, U0i, U1i, U00f, U01f, U10f, U11f,
                       U0o, U1o, U0u, U1u, Wt2, Ut2);

    hipLaunchKernelGGL(leaf_v3, dim3(NLEAF / 8), dim3(256), 0, stream,
                       Wt2, bi, bo, bu, emb, words, H, C);

    for (int d = 11; d >= 5; --d) {
        int s = (1 << d) - 1, count = 1 << d;
        if (d == 11) {
            hipLaunchKernelGGL(HIP_KERNEL_NAME(level_v3<8>), dim3((count + 7) / 8), dim3(512), 0, stream,
                               Ut2, bbi, bbf, bbo, bbu, lchs, rchs, H, C, s, count);
        } else {
            hipLaunchKernelGGL(HIP_KERNEL_NAME(level_v3<4>), dim3((count + 3) / 4), dim3(512), 0, stream,
                               Ut2, bbi, bbf, bbo, bbu, lchs, rchs, H, C, s, count);
        }
    }

    hipLaunchKernelGGL(tail_v3, dim3(1), dim3(512), 0, stream,
                       Ut2, bbi, bbf, bbo, bbu, lchs, rchs, H, C);

    hipLaunchKernelGGL(loss_kernel, dim3(LOSS_BLOCKS), dim3(256), 0, stream,
                       H, Why, by, scores, partials);
    hipLaunchKernelGGL(loss_final, dim3(1), dim3(64), 0, stream,
                       partials, out, LOSS_BLOCKS);
}

// Round 2
// 462.861 us; speedup vs baseline: 1.0776x; 1.0776x over previous
//
#include <hip/hip_runtime.h>
#include <math.h>

#define HID 150
#define EMB 300
#define NOUT 5
#define NNODES 8191
#define NLEAF 4096
#define LEAF_START 4095
#define HSTR 152          // padded H/C row stride (608 B, 16B-aligned rows)
#define XSTR 20           // LDS x-tile stride (80 B rows, 16B-aligned)
#define UCOLS 768         // 750 gate-cols + 18 pad = 256*3 (wave-even col mapping)
#define WCOLS 452         // 450 leaf-cols + 2 pad (1808 B rows)

constexpr int LOSS_BLOCKS = 64;

__device__ __forceinline__ float sigmoidf_(float x) { return 1.0f / (1.0f + __expf(-x)); }

// ---------------- prep: transpose weights to e-major, zero-pad ----------------
// Wt2[e][j], j: 0..149 Wi | 150..299 Wo | 300..449 Wu | 450..451 zero
// Ut2[e][j], j: g*150+h, g: 0=i,1=fl,2=fr,3=o,4=u; e<150 left (U0*), e>=150 right (U1*); 750..767 zero
__global__ __launch_bounds__(256) void prep_kernel(
    const float* __restrict__ Wi, const float* __restrict__ Wo, const float* __restrict__ Wu,
    const float* __restrict__ U0i, const float* __restrict__ U1i,
    const float* __restrict__ U00f, const float* __restrict__ U01f,
    const float* __restrict__ U10f, const float* __restrict__ U11f,
    const float* __restrict__ U0o, const float* __restrict__ U1o,
    const float* __restrict__ U0u, const float* __restrict__ U1u,
    float* __restrict__ Wt2, float* __restrict__ Ut2)
{
    int idx = blockIdx.x * 256 + threadIdx.x;
    if (idx < EMB * WCOLS) {
        int e = idx / WCOLS, j = idx - e * WCOLS;
        float v = 0.f;
        if (j < 450) {
            const float* W; int h;
            if (j < 150)      { W = Wi; h = j; }
            else if (j < 300) { W = Wo; h = j - 150; }
            else              { W = Wu; h = j - 300; }
            v = W[h * EMB + e];
        }
        Wt2[idx] = v;
    }
    if (idx < EMB * UCOLS) {
        int e = idx / UCOLS, j = idx - e * UCOLS;
        float v = 0.f;
        if (j < 750) {
            int g = j / 150, h = j - g * 150;
            if (e < 150) {
                const float* U = (g == 0) ? U0i : (g == 1) ? U00f : (g == 2) ? U10f : (g == 3) ? U0o : U0u;
                v = U[h * HID + e];
            } else {
                const float* U = (g == 0) ? U1i : (g == 1) ? U01f : (g == 2) ? U11f : (g == 3) ? U1o : U1u;
                v = U[h * HID + (e - 150)];
            }
        }
        Ut2[idx] = v;
    }
}

// ---------------- leaf: NB=8 leaves/block, 256 threads, k-split x2 ----------------
// threads: half = tid>>7 owns K-range [half*150, half*150+150); c = tid&127, c<113 owns cols 4c..4c+3.
// Each half accumulates into its own Gs buffer; epilogue sums.
__global__ __launch_bounds__(256) void leaf_v3(
    const float* __restrict__ Wt2,
    const float* __restrict__ bi, const float* __restrict__ bo, const float* __restrict__ bu,
    const float* __restrict__ emb, const int* __restrict__ words,
    float* __restrict__ H, float* __restrict__ C)
{
    constexpr int NB = 8;
    __shared__ __align__(16) float Xs[EMB * XSTR];
    __shared__ __align__(16) float Gs[2][NB][WCOLS];
    const int tid = threadIdx.x;
    const int leaf0 = LEAF_START + blockIdx.x * NB;

    for (int m = 0; m < NB; ++m) {
        const float* src = emb + (long)words[leaf0 + m] * EMB;
        for (int e = tid; e < EMB; e += 256) Xs[e * XSTR + m] = src[e];
    }
    __syncthreads();

    {
        const int half = tid >> 7;
        const int c = tid & 127;
        if (c < 113) {
            float acc[NB][4];
#pragma unroll
            for (int m = 0; m < NB; ++m)
#pragma unroll
                for (int q = 0; q < 4; ++q) acc[m][q] = 0.f;

            const int kbase = half * 150;
            const float* wp = Wt2 + (long)kbase * WCOLS + c * 4;
            const float* xp = Xs + kbase * XSTR;
#pragma unroll 4
            for (int k = 0; k < 150; ++k) {
                float4 w = *(const float4*)(wp + (long)k * WCOLS);
                float x[NB];
#pragma unroll
                for (int m = 0; m < NB; ++m) x[m] = xp[k * XSTR + m];
#pragma unroll
                for (int m = 0; m < NB; ++m) {
                    acc[m][0] = fmaf(x[m], w.x, acc[m][0]);
                    acc[m][1] = fmaf(x[m], w.y, acc[m][1]);
                    acc[m][2] = fmaf(x[m], w.z, acc[m][2]);
                    acc[m][3] = fmaf(x[m], w.w, acc[m][3]);
                }
            }
#pragma unroll
            for (int m = 0; m < NB; ++m)
                *(float4*)&Gs[half][m][c * 4] = make_float4(acc[m][0], acc[m][1], acc[m][2], acc[m][3]);
        }
    }
    __syncthreads();

    for (int p = tid; p < NB * HID; p += 256) {
        int m = p / HID, h = p - m * HID;
        float gi = Gs[0][m][h]       + Gs[1][m][h];
        float go = Gs[0][m][150 + h] + Gs[1][m][150 + h];
        float gu = Gs[0][m][300 + h] + Gs[1][m][300 + h];
        float ig = sigmoidf_(gi + bi[h]);
        float og = sigmoidf_(go + bo[h]);
        float uv = tanhf(gu + bu[h]);
        float cc = ig * uv;
        float hh = og * tanhf(cc);
        long node = leaf0 + m;
        H[node * HSTR + h] = hh;
        C[node * HSTR + h] = cc;
    }
}

// ---------------- internal level: NB nodes/block, 512 threads, k-split x2, 3-col-strided ----------------
// half = tid>>8 owns K-range [half*150,+150); c = tid&255 owns cols {c, c+256, c+512} of UCOLS=768.
// ALL 512 threads active -> 8 equal waves, 2/SIMD, even packing.
// NB chosen per level as max(1, count/256): never more than 1 block/CU, so each
// block's ~921.6 KB Ut2 L2-stream (the per-block floor at ~150 GB/s/CU) runs
// once per CU and in parallel across CUs.
template<int NB>
__global__ __launch_bounds__(512) void level_v3(
    const float* __restrict__ Ut2,
    const float* __restrict__ bbi, const float* __restrict__ bbf,
    const float* __restrict__ bbo, const float* __restrict__ bbu,
    const int* __restrict__ lchs, const int* __restrict__ rchs,
    float* __restrict__ H, float* __restrict__ C, int s, int count)
{
    __shared__ __align__(16) float Xs[EMB * XSTR];
    __shared__ __align__(16) float Gs[2][NB][UCOLS];
    __shared__ int lidx[NB], ridx[NB];
    const int tid = threadIdx.x;
    const int node0 = s + blockIdx.x * NB;
    int nb = count - blockIdx.x * NB; if (nb > NB) nb = NB;

    if (tid < NB) {
        int mm = tid < nb ? tid : 0;
        lidx[tid] = lchs[node0 + mm];
        ridx[tid] = rchs[node0 + mm];
    }
    __syncthreads();

    for (int m = 0; m < NB; ++m) {
        const float* hl = H + (long)lidx[m] * HSTR;
        const float* hr = H + (long)ridx[m] * HSTR;
        for (int e = tid; e < EMB; e += 512)
            Xs[e * XSTR + m] = (e < HID) ? hl[e] : hr[e - HID];
    }
    __syncthreads();

    {
        const int half = tid >> 8;
        const int c = tid & 255;
        float acc[NB][3];
#pragma unroll
        for (int m = 0; m < NB; ++m) { acc[m][0] = 0.f; acc[m][1] = 0.f; acc[m][2] = 0.f; }

        const int kbase = half * 150;
        const float* wp = Ut2 + (long)kbase * UCOLS + c;
        const float* xp = Xs + kbase * XSTR;
#pragma unroll 4
        for (int k = 0; k < 150; ++k) {
            float w0 = wp[(long)k * UCOLS];
            float w1 = wp[(long)k * UCOLS + 256];
            float w2 = wp[(long)k * UCOLS + 512];
            float x[NB];
#pragma unroll
            for (int m = 0; m < NB; ++m) x[m] = xp[k * XSTR + m];
#pragma unroll
            for (int m = 0; m < NB; ++m) {
                acc[m][0] = fmaf(x[m], w0, acc[m][0]);
                acc[m][1] = fmaf(x[m], w1, acc[m][1]);
                acc[m][2] = fmaf(x[m], w2, acc[m][2]);
            }
        }
#pragma unroll
        for (int m = 0; m < NB; ++m) {
            Gs[half][m][c]       = acc[m][0];
            Gs[half][m][c + 256] = acc[m][1];
            Gs[half][m][c + 512] = acc[m][2];
        }
    }
    __syncthreads();

    for (int p = tid; p < nb * HID; p += 512) {
        int m = p / HID, h = p - m * HID;
        float gi = Gs[0][m][h]       + Gs[1][m][h];
        float gf0= Gs[0][m][150 + h] + Gs[1][m][150 + h];
        float gf1= Gs[0][m][300 + h] + Gs[1][m][300 + h];
        float go = Gs[0][m][450 + h] + Gs[1][m][450 + h];
        float gu = Gs[0][m][600 + h] + Gs[1][m][600 + h];
        float ig = sigmoidf_(gi + bbi[h]);
        float fl = sigmoidf_(gf0 + bbf[h]);
        float fr = sigmoidf_(gf1 + bbf[h]);
        float og = sigmoidf_(go + bbo[h]);
        float uv = tanhf(gu + bbu[h]);
        float lc = C[(long)lidx[m] * HSTR + h];
        float rc = C[(long)ridx[m] * HSTR + h];
        float cc = ig * uv + fl * lc + fr * rc;
        float hh = og * tanhf(cc);
        long node = node0 + m;
        H[node * HSTR + h] = hh;
        C[node * HSTR + h] = cc;
    }
}

// ---------------- loss ----------------
__global__ __launch_bounds__(256) void loss_kernel(
    const float* __restrict__ H, const float* __restrict__ Why,
    const float* __restrict__ by, const int* __restrict__ scores,
    float* __restrict__ partials)
{
    __shared__ __align__(16) float Wys[NOUT][HSTR];
    __shared__ float bys[NOUT];
    __shared__ float red[256];
    int tid = threadIdx.x;
    for (int i = tid; i < NOUT * HID; i += 256) {
        int g = i / HID, k = i - g * HID;
        Wys[g][k] = Why[g * HID + k];
    }
    if (tid < NOUT) bys[tid] = by[tid];
    __syncthreads();

    float local = 0.f;
    for (int n = blockIdx.x * 256 + tid; n < NNODES; n += gridDim.x * 256) {
        const float* hr = H + (long)n * HSTR;
        float l0 = bys[0], l1 = bys[1], l2 = bys[2], l3 = bys[3], l4 = bys[4];
        for (int k = 0; k < 148; k += 4) {
            float4 hv = *(const float4*)(hr + k);
            float4 w0 = *(const float4*)&Wys[0][k];
            float4 w1 = *(const float4*)&Wys[1][k];
            float4 w2 = *(const float4*)&Wys[2][k];
            float4 w3 = *(const float4*)&Wys[3][k];
            float4 w4 = *(const float4*)&Wys[4][k];
            l0 += hv.x*w0.x + hv.y*w0.y + hv.z*w0.z + hv.w*w0.w;
            l1 += hv.x*w1.x + hv.y*w1.y + hv.z*w1.z + hv.w*w1.w;
            l2 += hv.x*w2.x + hv.y*w2.y + hv.z*w2.z + hv.w*w2.w;
            l3 += hv.x*w3.x + hv.y*w3.y + hv.z*w3.z + hv.w*w3.w;
            l4 += hv.x*w4.x + hv.y*w4.y + hv.z*w4.z + hv.w*w4.w;
        }
        for (int k = 148; k < HID; ++k) {
            float hv = hr[k];
            l0 += hv * Wys[0][k]; l1 += hv * Wys[1][k]; l2 += hv * Wys[2][k];
            l3 += hv * Wys[3][k]; l4 += hv * Wys[4][k];
        }
        float mx = fmaxf(fmaxf(fmaxf(l0, l1), fmaxf(l2, l3)), l4);
        float se = __expf(l0 - mx) + __expf(l1 - mx) + __expf(l2 - mx) +
                   __expf(l3 - mx) + __expf(l4 - mx);
        float lse = mx + __logf(se);
        int sc = scores[n];
        float lsc = (sc == 0) ? l0 : (sc == 1) ? l1 : (sc == 2) ? l2 : (sc == 3) ? l3 : l4;
        local += lse - lsc;
    }
    red[tid] = local;
    __syncthreads();
    for (int st = 128; st > 0; st >>= 1) {
        if (tid < st) red[tid] += red[tid + st];
        __syncthreads();
    }
    if (tid == 0) partials[blockIdx.x] = red[0];
}

__global__ void loss_final(const float* __restrict__ partials, float* __restrict__ out, int nparts)
{
    if (threadIdx.x == 0 && blockIdx.x == 0) {
        float s = 0.f;
        for (int i = 0; i < nparts; ++i) s += partials[i];
        out[0] = s;
    }
}

extern "C" void kernel_launch(void* const* d_in, const int* in_sizes, int n_in,
                              void* d_out, int out_size, void* d_ws, size_t ws_size,
                              hipStream_t stream)
{
    const float* Wi   = (const float*)d_in[0];
    const float* bi   = (const float*)d_in[1];
    const float* Wo   = (const float*)d_in[2];
    const float* bo   = (const float*)d_in[3];
    const float* Wu   = (const float*)d_in[4];
    const float* bu   = (const float*)d_in[5];
    const float* U0i  = (const float*)d_in[6];
    const float* U1i  = (const float*)d_in[7];
    const float* bbi  = (const float*)d_in[8];
    const float* U00f = (const float*)d_in[9];
    const float* U01f = (const float*)d_in[10];
    const float* U10f = (const float*)d_in[11];
    const float* U11f = (const float*)d_in[12];
    const float* bbf  = (const float*)d_in[13];
    const float* U0o  = (const float*)d_in[14];
    const float* U1o  = (const float*)d_in[15];
    const float* bbo  = (const float*)d_in[16];
    const float* U0u  = (const float*)d_in[17];
    const float* U1u  = (const float*)d_in[18];
    const float* bbu  = (const float*)d_in[19];
    const float* Why  = (const float*)d_in[20];
    const float* by   = (const float*)d_in[21];
    const float* emb  = (const float*)d_in[22];
    const int* scores = (const int*)d_in[23];
    const int* words  = (const int*)d_in[24];
    const int* lchs   = (const int*)d_in[25];
    const int* rchs   = (const int*)d_in[26];

    float* ws = (float*)d_ws;
    float* Wt2 = ws;                                  // 300*452 = 135600
    float* Ut2 = Wt2 + EMB * WCOLS;                   // 300*768 = 230400
    float* H   = Ut2 + EMB * UCOLS;                   // 8191*152
    float* C   = H + (long)NNODES * HSTR;             // 8191*152
    float* partials = C + (long)NNODES * HSTR;        // 64
    float* out = (float*)d_out;

    hipLaunchKernelGGL(prep_kernel, dim3(900), dim3(256), 0, stream,
                       Wi, Wo, Wu, U0i, U1i, U00f, U01f, U10f, U11f,
                       U0o, U1o, U0u, U1u, Wt2, Ut2);

    hipLaunchKernelGGL(leaf_v3, dim3(NLEAF / 8), dim3(256), 0, stream,
                       Wt2, bi, bo, bu, emb, words, H, C);

    for (int d = 11; d >= 0; --d) {
        int s = (1 << d) - 1, count = 1 << d;
        if (d == 11) {
            hipLaunchKernelGGL(HIP_KERNEL_NAME(level_v3<8>), dim3(count / 8), dim3(512), 0, stream,
                               Ut2, bbi, bbf, bbo, bbu, lchs, rchs, H, C, s, count);
        } else if (d == 10) {
            hipLaunchKernelGGL(HIP_KERNEL_NAME(level_v3<4>), dim3(count / 4), dim3(512), 0, stream,
                               Ut2, bbi, bbf, bbo, bbu, lchs, rchs, H, C, s, count);
        } else if (d == 9) {
            hipLaunchKernelGGL(HIP_KERNEL_NAME(level_v3<2>), dim3(count / 2), dim3(512), 0, stream,
                               Ut2, bbi, bbf, bbo, bbu, lchs, rchs, H, C, s, count);
        } else {
            hipLaunchKernelGGL(HIP_KERNEL_NAME(level_v3<1>), dim3(count), dim3(512), 0, stream,
                               Ut2, bbi, bbf, bbo, bbu, lchs, rchs, H, C, s, count);
        }
    }

    hipLaunchKernelGGL(loss_kernel, dim3(LOSS_BLOCKS), dim3(256), 0, stream,
                       H, Why, by, scores, partials);
    hipLaunchKernelGGL(loss_final, dim3(1), dim3(64), 0, stream,
                       partials, out, LOSS_BLOCKS);
}

// Round 3
// 369.837 us; speedup vs baseline: 1.3486x; 1.2515x over previous
//
#include <hip/hip_runtime.h>
#include <math.h>

#define HID 150
#define EMB 300
#define NOUT 5
#define NNODES 8191
#define NLEAF 4096
#define LEAF_START 4095
#define HSTR 152          // padded H/C row stride (608 B, 16B-aligned rows)
#define UCOLS 768         // padded gate-col count (both chunked layouts)
#define WCOLS 452         // 450 leaf-cols + 2 pad (1808 B rows)

constexpr int LOSS_BLOCKS = 64;

__device__ __forceinline__ float sigmoidf_(float x) { return 1.0f / (1.0f + __expf(-x)); }

// ---------------- prep: build chunk-major weight layouts ----------------
// Wt2[e][j] (WCOLS): j: 0..149 Wi | 150..299 Wo | 300..449 Wu | 450..451 zero
// Ut3[e][j] (HS=3): j = hc*256 + g*50 + h', hc<3, h'=h-hc*50; cols 250..255/chunk zero
// Ut4[e][j] (HS=6): j = hc*128 + g*25 + h', hc<6, h'=h-hc*25; cols 125..127/chunk zero
// gate g: 0=i, 1=fl, 2=fr, 3=o, 4=u; e<150 -> left (U0*), e>=150 -> right (U1*)
__global__ __launch_bounds__(256) void prep_kernel(
    const float* __restrict__ Wi, const float* __restrict__ Wo, const float* __restrict__ Wu,
    const float* __restrict__ U0i, const float* __restrict__ U1i,
    const float* __restrict__ U00f, const float* __restrict__ U01f,
    const float* __restrict__ U10f, const float* __restrict__ U11f,
    const float* __restrict__ U0o, const float* __restrict__ U1o,
    const float* __restrict__ U0u, const float* __restrict__ U1u,
    float* __restrict__ Wt2, float* __restrict__ Ut3, float* __restrict__ Ut4)
{
    int idx = blockIdx.x * 256 + threadIdx.x;
    if (idx < EMB * WCOLS) {
        int e = idx / WCOLS, j = idx - e * WCOLS;
        float v = 0.f;
        if (j < 450) {
            const float* W; int h;
            if (j < 150)      { W = Wi; h = j; }
            else if (j < 300) { W = Wo; h = j - 150; }
            else              { W = Wu; h = j - 300; }
            v = W[h * EMB + e];
        }
        Wt2[idx] = v;
    }
    if (idx < EMB * UCOLS) {
        int e = idx / UCOLS, j = idx - e * UCOLS;
        const float* U0[5] = {U0i, U00f, U10f, U0o, U0u};
        const float* U1[5] = {U1i, U01f, U11f, U1o, U1u};
        // HS=3 layout
        {
            int hc = j >> 8, cw = j & 255;
            float v = 0.f;
            if (cw < 250) {
                int g = cw / 50, hp = cw - g * 50, h = hc * 50 + hp;
                v = (e < 150) ? U0[g][h * HID + e] : U1[g][h * HID + (e - 150)];
            }
            Ut3[idx] = v;
        }
        // HS=6 layout
        {
            int hc = j >> 7, cw = j & 127;
            float v = 0.f;
            if (cw < 125) {
                int g = cw / 25, hp = cw - g * 25, h = hc * 25 + hp;
                v = (e < 150) ? U0[g][h * HID + e] : U1[g][h * HID + (e - 150)];
            }
            Ut4[idx] = v;
        }
    }
}

// ---------------- leaf: NB=8 leaves/block, 256 threads, k-split x2 ----------------
__global__ __launch_bounds__(256) void leaf_v3(
    const float* __restrict__ Wt2,
    const float* __restrict__ bi, const float* __restrict__ bo, const float* __restrict__ bu,
    const float* __restrict__ emb, const int* __restrict__ words,
    float* __restrict__ H, float* __restrict__ C)
{
    constexpr int NB = 8;
    __shared__ __align__(16) float Xs[EMB * NB];
    __shared__ __align__(16) float Gs[2][NB][WCOLS];
    const int tid = threadIdx.x;
    const int leaf0 = LEAF_START + blockIdx.x * NB;

    for (int m = 0; m < NB; ++m) {
        const float* src = emb + (long)words[leaf0 + m] * EMB;
        for (int e = tid; e < EMB; e += 256) Xs[e * NB + m] = src[e];
    }
    __syncthreads();

    {
        const int half = tid >> 7;
        const int c = tid & 127;
        if (c < 113) {
            float acc[NB][4];
#pragma unroll
            for (int m = 0; m < NB; ++m)
#pragma unroll
                for (int q = 0; q < 4; ++q) acc[m][q] = 0.f;

            const int kbase = half * 150;
            const float* wp = Wt2 + (long)kbase * WCOLS + c * 4;
            const float* xp = Xs + kbase * NB;
#pragma unroll 4
            for (int k = 0; k < 150; ++k) {
                float4 w = *(const float4*)(wp + (long)k * WCOLS);
                float4 xa = *(const float4*)(xp + k * NB);
                float4 xb = *(const float4*)(xp + k * NB + 4);
                float x[NB] = {xa.x, xa.y, xa.z, xa.w, xb.x, xb.y, xb.z, xb.w};
#pragma unroll
                for (int m = 0; m < NB; ++m) {
                    acc[m][0] = fmaf(x[m], w.x, acc[m][0]);
                    acc[m][1] = fmaf(x[m], w.y, acc[m][1]);
                    acc[m][2] = fmaf(x[m], w.z, acc[m][2]);
                    acc[m][3] = fmaf(x[m], w.w, acc[m][3]);
                }
            }
#pragma unroll
            for (int m = 0; m < NB; ++m)
                *(float4*)&Gs[half][m][c * 4] = make_float4(acc[m][0], acc[m][1], acc[m][2], acc[m][3]);
        }
    }
    __syncthreads();

    for (int p = tid; p < NB * HID; p += 256) {
        int m = p / HID, h = p - m * HID;
        float gi = Gs[0][m][h]       + Gs[1][m][h];
        float go = Gs[0][m][150 + h] + Gs[1][m][150 + h];
        float gu = Gs[0][m][300 + h] + Gs[1][m][300 + h];
        float ig = sigmoidf_(gi + bi[h]);
        float og = sigmoidf_(go + bo[h]);
        float uv = tanhf(gu + bu[h]);
        float cc = ig * uv;
        float hh = og * tanhf(cc);
        long node = leaf0 + m;
        H[node * HSTR + h] = hh;
        C[node * HSTR + h] = cc;
    }
}

// ---------------- internal level, HS=3: block = (node-group, h-chunk of 50) ----------------
// grid = (count/NB)*3. 512 threads: kq = tid>>7 owns K-range [kq*75,+75);
// c2 = tid&127 owns cols {2c2, 2c2+1} of the 256-col chunk. Per-block Ut3 stream = 307 KB.
template<int NB>
__global__ __launch_bounds__(512) void level_h3(
    const float* __restrict__ Ut3,
    const float* __restrict__ bbi, const float* __restrict__ bbf,
    const float* __restrict__ bbo, const float* __restrict__ bbu,
    const int* __restrict__ lchs, const int* __restrict__ rchs,
    float* __restrict__ H, float* __restrict__ C, int s)
{
    __shared__ __align__(16) float Xs[EMB * NB];
    __shared__ __align__(16) float Gs[4][NB][256];
    __shared__ int lidx[NB], ridx[NB];
    const int tid = threadIdx.x;
    const int grp = blockIdx.x / 3, hc = blockIdx.x % 3;
    const int node0 = s + grp * NB;

    if (tid < NB) {
        lidx[tid] = lchs[node0 + tid];
        ridx[tid] = rchs[node0 + tid];
    }
    __syncthreads();

    for (int m = 0; m < NB; ++m) {
        const float* hl = H + (long)lidx[m] * HSTR;
        const float* hr = H + (long)ridx[m] * HSTR;
        for (int e = tid; e < EMB; e += 512)
            Xs[e * NB + m] = (e < HID) ? hl[e] : hr[e - HID];
    }
    __syncthreads();

    {
        const int kq = tid >> 7, c2 = tid & 127;
        float acc[NB][2];
#pragma unroll
        for (int m = 0; m < NB; ++m) { acc[m][0] = 0.f; acc[m][1] = 0.f; }

        const float* wp = Ut3 + (long)(kq * 75) * UCOLS + hc * 256 + 2 * c2;
        const float* xp = Xs + (kq * 75) * NB;
#pragma unroll 5
        for (int k = 0; k < 75; ++k) {
            float2 w = *(const float2*)(wp + (long)k * UCOLS);
            float x[NB];
            if constexpr (NB == 8) {
                float4 a = *(const float4*)(xp + k * 8);
                float4 b = *(const float4*)(xp + k * 8 + 4);
                x[0]=a.x; x[1]=a.y; x[2]=a.z; x[3]=a.w;
                x[4]=b.x; x[5]=b.y; x[6]=b.z; x[7]=b.w;
            } else if constexpr (NB == 4) {
                float4 a = *(const float4*)(xp + k * 4);
                x[0]=a.x; x[1]=a.y; x[2]=a.z; x[3]=a.w;
            } else if constexpr (NB == 2) {
                float2 a = *(const float2*)(xp + k * 2);
                x[0]=a.x; x[1]=a.y;
            } else {
                x[0] = xp[k];
            }
#pragma unroll
            for (int m = 0; m < NB; ++m) {
                acc[m][0] = fmaf(x[m], w.x, acc[m][0]);
                acc[m][1] = fmaf(x[m], w.y, acc[m][1]);
            }
        }
#pragma unroll
        for (int m = 0; m < NB; ++m)
            *(float2*)&Gs[kq][m][2 * c2] = make_float2(acc[m][0], acc[m][1]);
    }
    __syncthreads();

    for (int p = tid; p < NB * 50; p += 512) {
        int m = p / 50, hp = p - m * 50, h = hc * 50 + hp;
        float gi  = Gs[0][m][hp]       + Gs[1][m][hp]       + Gs[2][m][hp]       + Gs[3][m][hp];
        float gf0 = Gs[0][m][50 + hp]  + Gs[1][m][50 + hp]  + Gs[2][m][50 + hp]  + Gs[3][m][50 + hp];
        float gf1 = Gs[0][m][100 + hp] + Gs[1][m][100 + hp] + Gs[2][m][100 + hp] + Gs[3][m][100 + hp];
        float go  = Gs[0][m][150 + hp] + Gs[1][m][150 + hp] + Gs[2][m][150 + hp] + Gs[3][m][150 + hp];
        float gu  = Gs[0][m][200 + hp] + Gs[1][m][200 + hp] + Gs[2][m][200 + hp] + Gs[3][m][200 + hp];
        float ig = sigmoidf_(gi + bbi[h]);
        float fl = sigmoidf_(gf0 + bbf[h]);
        float fr = sigmoidf_(gf1 + bbf[h]);
        float og = sigmoidf_(go + bbo[h]);
        float uv = tanhf(gu + bbu[h]);
        float lc = C[(long)lidx[m] * HSTR + h];
        float rc = C[(long)ridx[m] * HSTR + h];
        float cc = ig * uv + fl * lc + fr * rc;
        float hh = og * tanhf(cc);
        long node = node0 + m;
        H[node * HSTR + h] = hh;
        C[node * HSTR + h] = cc;
    }
}

// ---------------- internal level, HS=6: 1 node, h-chunk of 25 per block ----------------
// grid = count*6. Per-block Ut4 stream = 153.6 KB; deep unroll for load pipelining.
__global__ __launch_bounds__(512) void level_h6(
    const float* __restrict__ Ut4,
    const float* __restrict__ bbi, const float* __restrict__ bbf,
    const float* __restrict__ bbo, const float* __restrict__ bbu,
    const int* __restrict__ lchs, const int* __restrict__ rchs,
    float* __restrict__ H, float* __restrict__ C, int s)
{
    __shared__ __align__(16) float Xs[EMB];
    __shared__ __align__(16) float Gs[4][128];
    __shared__ int lr[2];
    const int tid = threadIdx.x;
    const int grp = blockIdx.x / 6, hc = blockIdx.x % 6;
    const int node = s + grp;

    if (tid < 2) lr[tid] = tid ? rchs[node] : lchs[node];
    __syncthreads();
    if (tid < EMB)
        Xs[tid] = (tid < HID) ? H[(long)lr[0] * HSTR + tid] : H[(long)lr[1] * HSTR + (tid - HID)];
    __syncthreads();

    {
        const int kq = tid >> 7, c = tid & 127;
        float acc = 0.f;
        const float* wp = Ut4 + (long)(kq * 75) * UCOLS + hc * 128 + c;
        const float* xp = Xs + kq * 75;
#pragma unroll 15
        for (int k = 0; k < 75; ++k)
            acc = fmaf(xp[k], wp[(long)k * UCOLS], acc);
        Gs[kq][c] = acc;
    }
    __syncthreads();

    if (tid < 25) {
        int hp = tid, h = hc * 25 + hp;
        float gi  = Gs[0][hp]       + Gs[1][hp]       + Gs[2][hp]       + Gs[3][hp];
        float gf0 = Gs[0][25 + hp]  + Gs[1][25 + hp]  + Gs[2][25 + hp]  + Gs[3][25 + hp];
        float gf1 = Gs[0][50 + hp]  + Gs[1][50 + hp]  + Gs[2][50 + hp]  + Gs[3][50 + hp];
        float go  = Gs[0][75 + hp]  + Gs[1][75 + hp]  + Gs[2][75 + hp]  + Gs[3][75 + hp];
        float gu  = Gs[0][100 + hp] + Gs[1][100 + hp] + Gs[2][100 + hp] + Gs[3][100 + hp];
        float ig = sigmoidf_(gi + bbi[h]);
        float fl = sigmoidf_(gf0 + bbf[h]);
        float fr = sigmoidf_(gf1 + bbf[h]);
        float og = sigmoidf_(go + bbo[h]);
        float uv = tanhf(gu + bbu[h]);
        float lc = C[(long)lr[0] * HSTR + h];
        float rc = C[(long)lr[1] * HSTR + h];
        float cc = ig * uv + fl * lc + fr * rc;
        float hh = og * tanhf(cc);
        H[(long)node * HSTR + h] = hh;
        C[(long)node * HSTR + h] = cc;
    }
}

// ---------------- loss ----------------
__global__ __launch_bounds__(256) void loss_kernel(
    const float* __restrict__ H, const float* __restrict__ Why,
    const float* __restrict__ by, const int* __restrict__ scores,
    float* __restrict__ partials)
{
    __shared__ __align__(16) float Wys[NOUT][HSTR];
    __shared__ float bys[NOUT];
    __shared__ float red[256];
    int tid = threadIdx.x;
    for (int i = tid; i < NOUT * HID; i += 256) {
        int g = i / HID, k = i - g * HID;
        Wys[g][k] = Why[g * HID + k];
    }
    if (tid < NOUT) bys[tid] = by[tid];
    __syncthreads();

    float local = 0.f;
    for (int n = blockIdx.x * 256 + tid; n < NNODES; n += gridDim.x * 256) {
        const float* hr = H + (long)n * HSTR;
        float l0 = bys[0], l1 = bys[1], l2 = bys[2], l3 = bys[3], l4 = bys[4];
        for (int k = 0; k < 148; k += 4) {
            float4 hv = *(const float4*)(hr + k);
            float4 w0 = *(const float4*)&Wys[0][k];
            float4 w1 = *(const float4*)&Wys[1][k];
            float4 w2 = *(const float4*)&Wys[2][k];
            float4 w3 = *(const float4*)&Wys[3][k];
            float4 w4 = *(const float4*)&Wys[4][k];
            l0 += hv.x*w0.x + hv.y*w0.y + hv.z*w0.z + hv.w*w0.w;
            l1 += hv.x*w1.x + hv.y*w1.y + hv.z*w1.z + hv.w*w1.w;
            l2 += hv.x*w2.x + hv.y*w2.y + hv.z*w2.z + hv.w*w2.w;
            l3 += hv.x*w3.x + hv.y*w3.y + hv.z*w3.z + hv.w*w3.w;
            l4 += hv.x*w4.x + hv.y*w4.y + hv.z*w4.z + hv.w*w4.w;
        }
        for (int k = 148; k < HID; ++k) {
            float hv = hr[k];
            l0 += hv * Wys[0][k]; l1 += hv * Wys[1][k]; l2 += hv * Wys[2][k];
            l3 += hv * Wys[3][k]; l4 += hv * Wys[4][k];
        }
        float mx = fmaxf(fmaxf(fmaxf(l0, l1), fmaxf(l2, l3)), l4);
        float se = __expf(l0 - mx) + __expf(l1 - mx) + __expf(l2 - mx) +
                   __expf(l3 - mx) + __expf(l4 - mx);
        float lse = mx + __logf(se);
        int sc = scores[n];
        float lsc = (sc == 0) ? l0 : (sc == 1) ? l1 : (sc == 2) ? l2 : (sc == 3) ? l3 : l4;
        local += lse - lsc;
    }
    red[tid] = local;
    __syncthreads();
    for (int st = 128; st > 0; st >>= 1) {
        if (tid < st) red[tid] += red[tid + st];
        __syncthreads();
    }
    if (tid == 0) partials[blockIdx.x] = red[0];
}

__global__ void loss_final(const float* __restrict__ partials, float* __restrict__ out, int nparts)
{
    if (threadIdx.x == 0 && blockIdx.x == 0) {
        float s = 0.f;
        for (int i = 0; i < nparts; ++i) s += partials[i];
        out[0] = s;
    }
}

extern "C" void kernel_launch(void* const* d_in, const int* in_sizes, int n_in,
                              void* d_out, int out_size, void* d_ws, size_t ws_size,
                              hipStream_t stream)
{
    const float* Wi   = (const float*)d_in[0];
    const float* bi   = (const float*)d_in[1];
    const float* Wo   = (const float*)d_in[2];
    const float* bo   = (const float*)d_in[3];
    const float* Wu   = (const float*)d_in[4];
    const float* bu   = (const float*)d_in[5];
    const float* U0i  = (const float*)d_in[6];
    const float* U1i  = (const float*)d_in[7];
    const float* bbi  = (const float*)d_in[8];
    const float* U00f = (const float*)d_in[9];
    const float* U01f = (const float*)d_in[10];
    const float* U10f = (const float*)d_in[11];
    const float* U11f = (const float*)d_in[12];
    const float* bbf  = (const float*)d_in[13];
    const float* U0o  = (const float*)d_in[14];
    const float* U1o  = (const float*)d_in[15];
    const float* bbo  = (const float*)d_in[16];
    const float* U0u  = (const float*)d_in[17];
    const float* U1u  = (const float*)d_in[18];
    const float* bbu  = (const float*)d_in[19];
    const float* Why  = (const float*)d_in[20];
    const float* by   = (const float*)d_in[21];
    const float* emb  = (const float*)d_in[22];
    const int* scores = (const int*)d_in[23];
    const int* words  = (const int*)d_in[24];
    const int* lchs   = (const int*)d_in[25];
    const int* rchs   = (const int*)d_in[26];

    float* ws = (float*)d_ws;
    float* Wt2 = ws;                                  // 300*452
    float* Ut3 = Wt2 + EMB * WCOLS;                   // 300*768 (HS=3 layout)
    float* Ut4 = Ut3 + EMB * UCOLS;                   // 300*768 (HS=6 layout)
    float* H   = Ut4 + EMB * UCOLS;                   // 8191*152
    float* C   = H + (long)NNODES * HSTR;             // 8191*152
    float* partials = C + (long)NNODES * HSTR;        // 64
    float* out = (float*)d_out;

    hipLaunchKernelGGL(prep_kernel, dim3(900), dim3(256), 0, stream,
                       Wi, Wo, Wu, U0i, U1i, U00f, U01f, U10f, U11f,
                       U0o, U1o, U0u, U1u, Wt2, Ut3, Ut4);

    hipLaunchKernelGGL(leaf_v3, dim3(NLEAF / 8), dim3(256), 0, stream,
                       Wt2, bi, bo, bu, emb, words, H, C);

    for (int d = 11; d >= 0; --d) {
        int s = (1 << d) - 1, count = 1 << d;
        if (d >= 10) {
            hipLaunchKernelGGL(HIP_KERNEL_NAME(level_h3<8>), dim3((count / 8) * 3), dim3(512), 0, stream,
                               Ut3, bbi, bbf, bbo, bbu, lchs, rchs, H, C, s);
        } else if (d == 9) {
            hipLaunchKernelGGL(HIP_KERNEL_NAME(level_h3<4>), dim3((count / 4) * 3), dim3(512), 0, stream,
                               Ut3, bbi, bbf, bbo, bbu, lchs, rchs, H, C, s);
        } else if (d == 8) {
            hipLaunchKernelGGL(HIP_KERNEL_NAME(level_h3<2>), dim3((count / 2) * 3), dim3(512), 0, stream,
                               Ut3, bbi, bbf, bbo, bbu, lchs, rchs, H, C, s);
        } else if (d == 7) {
            hipLaunchKernelGGL(HIP_KERNEL_NAME(level_h3<1>), dim3(count * 3), dim3(512), 0, stream,
                               Ut3, bbi, bbf, bbo, bbu, lchs, rchs, H, C, s);
        } else {
            hipLaunchKernelGGL(level_h6, dim3(count * 6), dim3(512), 0, stream,
                               Ut4, bbi, bbf, bbo, bbu, lchs, rchs, H, C, s);
        }
    }

    hipLaunchKernelGGL(loss_kernel, dim3(LOSS_BLOCKS), dim3(256), 0, stream,
                       H, Why, by, scores, partials);
    hipLaunchKernelGGL(loss_final, dim3(1), dim3(64), 0, stream,
                       partials, out, LOSS_BLOCKS);
}